// Round 12
// baseline (244.388 us; speedup 1.0000x reference)
//
#include <hip/hip_runtime.h>

#define NPTS 50000
#define KNB 16
#define FDIM 64
#define OUTC 64
#define FAN 1024   // KNB*FDIM
#define NBL 4      // n values per block

typedef __attribute__((ext_vector_type(4))) float f32x4;
typedef __attribute__((ext_vector_type(8))) short bf16x8;
typedef __attribute__((ext_vector_type(4))) short bf16x4;

__device__ __forceinline__ unsigned short f2bf(float f) {
    union { float f; unsigned u; } a; a.f = f;
    return (unsigned short)((a.u + 0x7fffu + ((a.u >> 16) & 1u)) >> 16);
}

// one-time (per launch) conversion of W [64][1024] f32 -> bf16 in d_ws
__global__ void wconv_kernel(const float* __restrict__ W, unsigned short* __restrict__ Wb) {
    int i = blockIdx.x * 256 + threadIdx.x;
    Wb[i] = f2bf(W[i]);
}

// one-time conversion of x [4*50000*64] f32 -> bf16 (halves gather fetch bytes)
__global__ void xconv_kernel(const float* __restrict__ x, unsigned short* __restrict__ xb) {
    int i = blockIdx.x * 256 + threadIdx.x;         // one bf16x4 group per thread
    f32x4 vx = *(const f32x4*)&x[(size_t)i * 4];
    bf16x4 o;
    #pragma unroll
    for (int d = 0; d < 4; ++d) o[d] = (short)f2bf(vx[d]);
    *(bf16x4*)&xb[(size_t)i * 4] = o;
}

// MODE: 0 = no workspace, 1 = Wb only, 2 = Wb + pre-converted bf16 x (asm deep-gather)
template<int MODE>
__global__ __launch_bounds__(256, 4)
void paiconv_kernel(const float* __restrict__ x, const unsigned short* __restrict__ xbf,
                    const float* __restrict__ v,
                    const float* __restrict__ aw, const float* __restrict__ W,
                    const unsigned short* __restrict__ Wb,
                    const float* __restrict__ bias, const int* __restrict__ nbr,
                    float* __restrict__ out)
{
    // yel rows padded to 1032 bf16 (2064 B): phase-2 b128 reads land on rotating banks.
    // Final storage is SWIZZLED: logical (t,f) lives at [t*64 + (f ^ ((t&7)<<3))].
    // Each row ALSO serves as the phase-1 staging buffer for its own point
    // (subtiled X layout, fully consumed into registers before outputs land).
    __shared__ __align__(16) unsigned short yel[16][1032]; // 33 KB
    __shared__ int idxs[4][4][KNB];                        // 1 KB

    const int tid  = threadIdx.x;
    const int w    = tid >> 6;   // wave id = which n of the 4
    const int lane = tid & 63;
    const int cl   = lane & 15;
    const int kg   = lane >> 4;  // 16-lane group 0..3
    const int n0   = blockIdx.x * NBL;
    const int n    = n0 + w;

    // neighbor indices for this wave's n: lane l -> (batch pp, k)
    idxs[w][lane >> 4][lane & 15] = nbr[((lane >> 4) * NPTS + n) * KNB + (lane & 15)];

    // ---- B operand for phase-1 MFMA: adj[k][t]; k-map k = kg*4+j (j=0..3), j>=4 zero ----
    f32x4 v0 = *(const f32x4*)&v[n * 8];
    f32x4 v1 = *(const f32x4*)&v[n * 8 + 4];
    float vv[8] = {v0[0], v0[1], v0[2], v0[3], v1[0], v1[1], v1[2], v1[3]};
    bf16x8 badj;
    #pragma unroll
    for (int j = 0; j < 4; ++j) {
        float a = 0.f;
        #pragma unroll
        for (int s = 0; s < 8; ++s) a += vv[s] * aw[s * 256 + (kg * 4 + j) * KNB + cl];
        badj[j] = (short)f2bf(a);
    }
    #pragma unroll
    for (int j = 4; j < 8; ++j) badj[j] = 0;

    // staging lane roles: instr i loads row k=i*4+g, f-chunk fq (coalesced)
    const int g  = lane >> 4;
    const int fq = lane & 15;

    if constexpr (MODE == 2) {
        // ======== phase 1, deep-pipelined: 16 asm gathers in flight ========
        // hoist all 16 neighbor indices (LDS -> regs; compiler inserts lgkm waits)
        int r00 = idxs[w][0][0*4+g], r01 = idxs[w][0][1*4+g], r02 = idxs[w][0][2*4+g], r03 = idxs[w][0][3*4+g];
        int r10 = idxs[w][1][0*4+g], r11 = idxs[w][1][1*4+g], r12 = idxs[w][1][2*4+g], r13 = idxs[w][1][3*4+g];
        int r20 = idxs[w][2][0*4+g], r21 = idxs[w][2][1*4+g], r22 = idxs[w][2][2*4+g], r23 = idxs[w][2][3*4+g];
        int r30 = idxs[w][3][0*4+g], r31 = idxs[w][3][1*4+g], r32 = idxs[w][3][2*4+g], r33 = idxs[w][3][3*4+g];

        // issue ALL 16 loads back-to-back (8B/lane: one bf16x4 of row (pp,ri)).
        // asm keeps them outstanding; OUR vmcnt governs consumption. Any elder/younger
        // compiler loads only make the counted waits more conservative (safe).
        uint2 q00, q01, q02, q03, q10, q11, q12, q13,
              q20, q21, q22, q23, q30, q31, q32, q33;
#define GL(Q, PP, RI) do { \
            const unsigned short* _p = &xbf[((size_t)(PP) * NPTS + (unsigned)(RI)) * FDIM + fq * 4]; \
            asm volatile("global_load_dwordx2 %0, %1, off" : "=v"(Q) : "v"(_p) : "memory"); \
        } while (0)
        GL(q00,0,r00); GL(q01,0,r01); GL(q02,0,r02); GL(q03,0,r03);
        GL(q10,1,r10); GL(q11,1,r11); GL(q12,1,r12); GL(q13,1,r13);
        GL(q20,2,r20); GL(q21,2,r21); GL(q22,2,r22); GL(q23,2,r23);
        GL(q30,3,r30); GL(q31,3,r31); GL(q32,3,r32); GL(q33,3,r33);
#undef GL

        // staging: elem = ft*256 + k*16 + fl, ft=fq>>2, fl=4*(lane&3); graded vmcnt
        const int wbase = (fq >> 2) * 256 + 4 * (lane & 3);
#define STAGE(PP, A, B, C, D) do { \
            unsigned short* _S = &yel[w * 4 + (PP)][0]; \
            union { uint2 u; bf16x4 b; } u0, u1, u2, u3; \
            u0.u = A; u1.u = B; u2.u = C; u3.u = D; \
            *(bf16x4*)&_S[wbase + (0 * 4 + g) * 16] = u0.b; \
            *(bf16x4*)&_S[wbase + (1 * 4 + g) * 16] = u1.b; \
            *(bf16x4*)&_S[wbase + (2 * 4 + g) * 16] = u2.b; \
            *(bf16x4*)&_S[wbase + (3 * 4 + g) * 16] = u3.b; \
        } while (0)
        asm volatile("s_waitcnt vmcnt(12)" ::: "memory");
        __builtin_amdgcn_sched_barrier(0);
        STAGE(0, q00, q01, q02, q03);
        asm volatile("s_waitcnt vmcnt(8)" ::: "memory");
        __builtin_amdgcn_sched_barrier(0);
        STAGE(1, q10, q11, q12, q13);
        asm volatile("s_waitcnt vmcnt(4)" ::: "memory");
        __builtin_amdgcn_sched_barrier(0);
        STAGE(2, q20, q21, q22, q23);
        asm volatile("s_waitcnt vmcnt(0)" ::: "memory");
        __builtin_amdgcn_sched_barrier(0);
        STAGE(3, q30, q31, q32, q33);
#undef STAGE

        // ONE drain: all staging writes visible before transpose-reads
        asm volatile("s_waitcnt lgkmcnt(0)" ::: "memory");
        __builtin_amdgcn_sched_barrier(0);

        // 16 transpose-reads (HK pattern): per-lane addr = row base + lane*8B;
        // lane l elem j = elem[(l&15) + j*16 + (l>>4)*64] of the 512B subtile ->
        // frs[pp][ft][j] = X[kg*4+j][ft*16+cl]. offset: walks the 4 f-subtiles.
        bf16x4 f00, f01, f02, f03, f10, f11, f12, f13,
               f20, f21, f22, f23, f30, f31, f32, f33;
#define TR4(PP, A, B, C, D) do { \
            unsigned _ab = (unsigned)(unsigned long long)&yel[w * 4 + (PP)][0] + lane * 8; \
            asm volatile("ds_read_b64_tr_b16 %0, %1 offset:0"    : "=v"(A) : "v"(_ab) : "memory"); \
            asm volatile("ds_read_b64_tr_b16 %0, %1 offset:512"  : "=v"(B) : "v"(_ab) : "memory"); \
            asm volatile("ds_read_b64_tr_b16 %0, %1 offset:1024" : "=v"(C) : "v"(_ab) : "memory"); \
            asm volatile("ds_read_b64_tr_b16 %0, %1 offset:1536" : "=v"(D) : "v"(_ab) : "memory"); \
        } while (0)
        TR4(0, f00, f01, f02, f03);
        TR4(1, f10, f11, f12, f13);
        TR4(2, f20, f21, f22, f23);
        TR4(3, f30, f31, f32, f33);
#undef TR4
        asm volatile("s_waitcnt lgkmcnt(0)" ::: "memory");
        __builtin_amdgcn_sched_barrier(0);

        // 16 MFMAs (K=16 padded to 32 with zero slots) + elu + swizzled outputs
#define MF(PP, FT, FR) do { \
            bf16x8 _af; \
            _af[0] = FR[0]; _af[1] = FR[1]; _af[2] = FR[2]; _af[3] = FR[3]; \
            _af[4] = 0; _af[5] = 0; _af[6] = 0; _af[7] = 0; \
            f32x4 _ac = {0.f, 0.f, 0.f, 0.f}; \
            _ac = __builtin_amdgcn_mfma_f32_16x16x32_bf16(_af, badj, _ac, 0, 0, 0); \
            const int _t  = cl; \
            const int _fs = ((FT) * 16 + kg * 4) ^ ((_t & 7) << 3); \
            bf16x4 _wv; \
            _Pragma("unroll") \
            for (int _r = 0; _r < 4; ++_r) { \
                float _e = _ac[_r]; \
                _e = _e > 0.f ? _e : __expf(_e) - 1.f; \
                _wv[_r] = (short)f2bf(_e); \
            } \
            *(bf16x4*)&yel[w * 4 + (PP)][_t * 64 + _fs] = _wv; \
        } while (0)
        MF(0,0,f00); MF(0,1,f01); MF(0,2,f02); MF(0,3,f03);
        MF(1,0,f10); MF(1,1,f11); MF(1,2,f12); MF(1,3,f13);
        MF(2,0,f20); MF(2,1,f21); MF(2,2,f22); MF(2,3,f23);
        MF(3,0,f30); MF(3,1,f31); MF(3,2,f32); MF(3,3,f33);
#undef MF
    } else {
        // ======== fallback phase 1 (f32 x, 1-deep prefetch) ========
        f32x4 fA[4];
        #pragma unroll
        for (int i = 0; i < 4; ++i) {
            int row = idxs[w][0][i * 4 + g];
            fA[i] = *(const f32x4*)&x[(size_t)row * FDIM + fq * 4];
        }
        #pragma unroll
        for (int pp = 0; pp < 4; ++pp) {
            f32x4 fB[4];
            if (pp < 3) {
                #pragma unroll
                for (int i = 0; i < 4; ++i) {
                    int row = idxs[w][pp + 1][i * 4 + g];
                    fB[i] = *(const f32x4*)&x[((size_t)(pp + 1) * NPTS + row) * FDIM + fq * 4];
                }
            }
            unsigned short* S = &yel[w * 4 + pp][0];
            {
                const int wbase = (fq >> 2) * 256 + 4 * (lane & 3);
                #pragma unroll
                for (int i = 0; i < 4; ++i) {
                    bf16x4 pkd;
                    #pragma unroll
                    for (int d = 0; d < 4; ++d) pkd[d] = (short)f2bf(fA[i][d]);
                    *(bf16x4*)&S[wbase + (i * 4 + g) * 16] = pkd;
                }
            }
            asm volatile("s_waitcnt lgkmcnt(0)" ::: "memory");
            __builtin_amdgcn_sched_barrier(0);
            bf16x4 fr0, fr1, fr2, fr3;
            {
                unsigned ab = (unsigned)(unsigned long long)&S[0] + lane * 8;
                asm volatile("ds_read_b64_tr_b16 %0, %1 offset:0"    : "=v"(fr0) : "v"(ab) : "memory");
                asm volatile("ds_read_b64_tr_b16 %0, %1 offset:512"  : "=v"(fr1) : "v"(ab) : "memory");
                asm volatile("ds_read_b64_tr_b16 %0, %1 offset:1024" : "=v"(fr2) : "v"(ab) : "memory");
                asm volatile("ds_read_b64_tr_b16 %0, %1 offset:1536" : "=v"(fr3) : "v"(ab) : "memory");
            }
            asm volatile("s_waitcnt lgkmcnt(0)" ::: "memory");
            __builtin_amdgcn_sched_barrier(0);
            bf16x4 frs[4] = {fr0, fr1, fr2, fr3};
            #pragma unroll
            for (int ft = 0; ft < 4; ++ft) {
                bf16x8 af;
                #pragma unroll
                for (int j = 0; j < 4; ++j) af[j] = frs[ft][j];
                #pragma unroll
                for (int j = 4; j < 8; ++j) af[j] = 0;
                f32x4 accv = {0.f, 0.f, 0.f, 0.f};
                accv = __builtin_amdgcn_mfma_f32_16x16x32_bf16(af, badj, accv, 0, 0, 0);
                const int t  = cl;
                const int fs = (ft * 16 + kg * 4) ^ ((t & 7) << 3);
                bf16x4 wv;
                #pragma unroll
                for (int r = 0; r < 4; ++r) {
                    float e = accv[r];
                    e = e > 0.f ? e : __expf(e) - 1.f;
                    wv[r] = (short)f2bf(e);
                }
                *(bf16x4*)&S[t * 64 + fs] = wv;
            }
            if (pp < 3) { fA[0] = fB[0]; fA[1] = fB[1]; fA[2] = fB[2]; fA[3] = fB[3]; }
        }
    }

    __syncthreads();

    // ---- phase 2: wave w owns C-tile rows=16 points, cols c in [16w,16w+16) ----
    const int c = w * 16 + cl;
    f32x4 acc = {0.f, 0.f, 0.f, 0.f};
    #pragma unroll 8
    for (int kt = 0; kt < 32; ++kt) {
        const int t  = kt >> 1;
        const int fs = (((kt & 1) * 32) | (kg * 8)) ^ ((t & 7) << 3);
        bf16x8 afrag = *(const bf16x8*)&yel[cl][t * 64 + fs];   // ds_read_b128
        bf16x8 bfrag;
        const int k0 = kt * 32 + kg * 8;
        if constexpr (MODE >= 1) {
            bfrag = *(const bf16x8*)&Wb[c * FAN + k0];
        } else {
            f32x4 w0 = *(const f32x4*)&W[c * FAN + k0];
            f32x4 w1 = *(const f32x4*)&W[c * FAN + k0 + 4];
            #pragma unroll
            for (int j = 0; j < 4; ++j) {
                bfrag[j]     = (short)f2bf(w0[j]);
                bfrag[j + 4] = (short)f2bf(w1[j]);
            }
        }
        acc = __builtin_amdgcn_mfma_f32_16x16x32_bf16(afrag, bfrag, acc, 0, 0, 0);
    }

    // epilogue: D row = kg*4 + r = local point, col = c
    float bc = bias[c];
    #pragma unroll
    for (int j = 0; j < 4; ++j) {
        int row = kg * 4 + j;
        int nn  = n0 + (row >> 2);
        int pp  = row & 3;
        float val = acc[j] + bc;
        val = val > 0.f ? val : __expf(val) - 1.f;
        if (nn == NPTS - 1) val = 0.f;   // zero_pad: last point zeroed (all b, all c)
        out[(pp * NPTS + nn) * FDIM + c] = val;
    }
}

extern "C" void kernel_launch(void* const* d_in, const int* in_sizes, int n_in,
                              void* d_out, int out_size, void* d_ws, size_t ws_size,
                              hipStream_t stream) {
    const float* x    = (const float*)d_in[0];
    const float* v    = (const float*)d_in[1];
    const float* aw   = (const float*)d_in[2];
    const float* W    = (const float*)d_in[3];
    const float* bias = (const float*)d_in[4];
    const int*   nbr  = (const int*)d_in[5];
    float* out = (float*)d_out;

    const size_t wb_bytes  = (size_t)OUTC * FAN * 2;            // 128 KB
    const size_t xbf_off   = 131072;                            // 128 KB, 16B-aligned
    const size_t xbf_bytes = (size_t)4 * NPTS * FDIM * 2;       // 25.6 MB

    dim3 grid(NPTS / NBL), blk(256);
    if (ws_size >= xbf_off + xbf_bytes) {
        unsigned short* Wb  = (unsigned short*)d_ws;
        unsigned short* xbf = (unsigned short*)((char*)d_ws + xbf_off);
        wconv_kernel<<<dim3(OUTC * FAN / 256), dim3(256), 0, stream>>>(W, Wb);
        xconv_kernel<<<dim3(4 * NPTS * FDIM / 1024), dim3(256), 0, stream>>>(x, xbf);
        paiconv_kernel<2><<<grid, blk, 0, stream>>>(x, xbf, v, aw, W, Wb, bias, nbr, out);
    } else if (ws_size >= wb_bytes) {
        unsigned short* Wb = (unsigned short*)d_ws;
        wconv_kernel<<<dim3(OUTC * FAN / 256), dim3(256), 0, stream>>>(W, Wb);
        paiconv_kernel<1><<<grid, blk, 0, stream>>>(x, (const unsigned short*)nullptr,
                                                    v, aw, W, Wb, bias, nbr, out);
    } else {
        paiconv_kernel<0><<<grid, blk, 0, stream>>>(x, (const unsigned short*)nullptr,
                                                    v, aw, W, (const unsigned short*)nullptr,
                                                    bias, nbr, out);
    }
}

// Round 13
// 228.589 us; speedup vs baseline: 1.0691x; 1.0691x over previous
//
#include <hip/hip_runtime.h>

#define NPTS 50000
#define KNB 16
#define FDIM 64
#define OUTC 64
#define FAN 1024   // KNB*FDIM
#define NBL 4      // n values per block

typedef __attribute__((ext_vector_type(4))) float f32x4;
typedef __attribute__((ext_vector_type(8))) short bf16x8;
typedef __attribute__((ext_vector_type(4))) short bf16x4;

__device__ __forceinline__ unsigned short f2bf(float f) {
    union { float f; unsigned u; } a; a.f = f;
    return (unsigned short)((a.u + 0x7fffu + ((a.u >> 16) & 1u)) >> 16);
}

// one-time (per launch) conversion of W [64][1024] f32 -> bf16 in d_ws
__global__ void wconv_kernel(const float* __restrict__ W, unsigned short* __restrict__ Wb) {
    int i = blockIdx.x * 256 + threadIdx.x;
    Wb[i] = f2bf(W[i]);
}

// one-time conversion of x [4*50000*64] f32 -> bf16 (halves gather fetch bytes)
__global__ void xconv_kernel(const float* __restrict__ x, unsigned short* __restrict__ xb) {
    int i = blockIdx.x * 256 + threadIdx.x;         // one bf16x4 group per thread
    f32x4 vx = *(const f32x4*)&x[(size_t)i * 4];
    bf16x4 o;
    #pragma unroll
    for (int d = 0; d < 4; ++d) o[d] = (short)f2bf(vx[d]);
    *(bf16x4*)&xb[(size_t)i * 4] = o;
}

// MODE: 0 = no workspace, 1 = Wb only, 2 = Wb + pre-converted bf16 x (8-rows/instr gather)
template<int MODE>
__global__ __launch_bounds__(256, 4)
void paiconv_kernel(const float* __restrict__ x, const unsigned short* __restrict__ xbf,
                    const float* __restrict__ v,
                    const float* __restrict__ aw, const float* __restrict__ W,
                    const unsigned short* __restrict__ Wb,
                    const float* __restrict__ bias, const int* __restrict__ nbr,
                    float* __restrict__ out)
{
    // yel rows padded to 1032 bf16 (2064 B): phase-2 b128 reads land on rotating banks.
    // Final storage is SWIZZLED: logical (t,f) lives at [t*64 + (f ^ ((t&7)<<3))].
    // Each row ALSO serves as the phase-1 staging buffer for its own point
    // (subtiled X layout, fully consumed into registers before outputs land).
    __shared__ __align__(16) unsigned short yel[16][1032]; // 33 KB
    __shared__ int idxs[4][4][KNB];                        // 1 KB

    const int tid  = threadIdx.x;
    const int w    = tid >> 6;   // wave id = which n of the 4
    const int lane = tid & 63;
    const int cl   = lane & 15;
    const int kg   = lane >> 4;  // 16-lane group 0..3
    const int n0   = blockIdx.x * NBL;
    const int n    = n0 + w;

    // neighbor indices for this wave's n: lane l -> (batch pp, k)
    idxs[w][lane >> 4][lane & 15] = nbr[((lane >> 4) * NPTS + n) * KNB + (lane & 15)];

    // ---- B operand for phase-1 MFMA: adj[k][t]; k-map k = kg*4+j (j=0..3), j>=4 zero ----
    f32x4 v0 = *(const f32x4*)&v[n * 8];
    f32x4 v1 = *(const f32x4*)&v[n * 8 + 4];
    float vv[8] = {v0[0], v0[1], v0[2], v0[3], v1[0], v1[1], v1[2], v1[3]};
    bf16x8 badj;
    #pragma unroll
    for (int j = 0; j < 4; ++j) {
        float a = 0.f;
        #pragma unroll
        for (int s = 0; s < 8; ++s) a += vv[s] * aw[s * 256 + (kg * 4 + j) * KNB + cl];
        badj[j] = (short)f2bf(a);
    }
    #pragma unroll
    for (int j = 4; j < 8; ++j) badj[j] = 0;

    if constexpr (MODE == 2) {
        // ======== phase 1: 8-rows-per-instruction gather (2 loads per pp) ========
        // lane role: row-in-group ri = lane>>3 (8 rows/instr), chunk c = lane&7 (16B).
        // Staging: k = j*8+ri, elems 8c..8c+8 -> subtile addr ft=c>>1, fl=8*(c&1):
        // one aligned b128 per lane, banks uniform (conflict-free).
        const int ri = lane >> 3;
        const int ch = lane & 7;
        const int sb = (ch >> 1) * 256 + 8 * (ch & 1);   // ft*256 + fl

        // prefetch pp=0 (2 instrs)
        uint4 qA0, qA1;
        {
            int r0 = idxs[w][0][ri], r1 = idxs[w][0][8 + ri];
            qA0 = *(const uint4*)&xbf[((size_t)0 * NPTS + r0) * FDIM + ch * 8];
            qA1 = *(const uint4*)&xbf[((size_t)0 * NPTS + r1) * FDIM + ch * 8];
        }

        #pragma unroll
        for (int pp = 0; pp < 4; ++pp) {
            uint4 qB0, qB1;
            if (pp < 3) {
                int r0 = idxs[w][pp + 1][ri], r1 = idxs[w][pp + 1][8 + ri];
                qB0 = *(const uint4*)&xbf[((size_t)(pp + 1) * NPTS + r0) * FDIM + ch * 8];
                qB1 = *(const uint4*)&xbf[((size_t)(pp + 1) * NPTS + r1) * FDIM + ch * 8];
            }

            unsigned short* S = &yel[w * 4 + pp][0];
            *(uint4*)&S[sb + (0 * 8 + ri) * 16] = qA0;   // ds_write_b128, uniform banks
            *(uint4*)&S[sb + (1 * 8 + ri) * 16] = qA1;

            // writes visible before transpose-reads
            asm volatile("s_waitcnt lgkmcnt(0)" ::: "memory");
            __builtin_amdgcn_sched_barrier(0);

            // transpose-reads (HK pattern): per-lane addr = row base + lane*8B;
            // lane l elem j = elem[(l&15) + j*16 + (l>>4)*64] of 512B subtile ->
            // fr_ft[j] = X[kg*4+j][ft*16+cl]. offset: walks the 4 f-subtiles.
            bf16x4 fr0, fr1, fr2, fr3;
            {
                unsigned ab = (unsigned)(unsigned long long)&S[0] + lane * 8;
                asm volatile("ds_read_b64_tr_b16 %0, %1 offset:0"    : "=v"(fr0) : "v"(ab) : "memory");
                asm volatile("ds_read_b64_tr_b16 %0, %1 offset:512"  : "=v"(fr1) : "v"(ab) : "memory");
                asm volatile("ds_read_b64_tr_b16 %0, %1 offset:1024" : "=v"(fr2) : "v"(ab) : "memory");
                asm volatile("ds_read_b64_tr_b16 %0, %1 offset:1536" : "=v"(fr3) : "v"(ab) : "memory");
            }
            asm volatile("s_waitcnt lgkmcnt(0)" ::: "memory");
            __builtin_amdgcn_sched_barrier(0);

            // 4 MFMAs (K=16 padded to 32 with zero slots) + elu + swizzled output
            bf16x4 frs[4] = {fr0, fr1, fr2, fr3};
            #pragma unroll
            for (int ft = 0; ft < 4; ++ft) {
                bf16x8 af;
                #pragma unroll
                for (int j = 0; j < 4; ++j) af[j] = frs[ft][j];
                #pragma unroll
                for (int j = 4; j < 8; ++j) af[j] = 0;
                f32x4 accv = {0.f, 0.f, 0.f, 0.f};
                accv = __builtin_amdgcn_mfma_f32_16x16x32_bf16(af, badj, accv, 0, 0, 0);
                // D: row(m) = kg*4+r -> f = ft*16+kg*4+r ; col(n) = cl -> t
                const int t  = cl;
                const int fs = (ft * 16 + kg * 4) ^ ((t & 7) << 3);
                bf16x4 wv;
                #pragma unroll
                for (int r = 0; r < 4; ++r) {
                    float e = accv[r];
                    e = e > 0.f ? e : __expf(e) - 1.f;
                    wv[r] = (short)f2bf(e);
                }
                *(bf16x4*)&S[t * 64 + fs] = wv;   // staging already consumed into frs
            }

            if (pp < 3) { qA0 = qB0; qA1 = qB1; }
        }
    } else {
        // ======== fallback phase 1 (f32 x, 16-lane/row mapping, 1-deep prefetch) ========
        const int g  = lane >> 4;
        const int fq = lane & 15;
        f32x4 fA[4];
        #pragma unroll
        for (int i = 0; i < 4; ++i) {
            int row = idxs[w][0][i * 4 + g];
            fA[i] = *(const f32x4*)&x[(size_t)row * FDIM + fq * 4];
        }
        #pragma unroll
        for (int pp = 0; pp < 4; ++pp) {
            f32x4 fB[4];
            if (pp < 3) {
                #pragma unroll
                for (int i = 0; i < 4; ++i) {
                    int row = idxs[w][pp + 1][i * 4 + g];
                    fB[i] = *(const f32x4*)&x[((size_t)(pp + 1) * NPTS + row) * FDIM + fq * 4];
                }
            }
            unsigned short* S = &yel[w * 4 + pp][0];
            {
                const int wbase = (fq >> 2) * 256 + 4 * (lane & 3);
                #pragma unroll
                for (int i = 0; i < 4; ++i) {
                    bf16x4 pkd;
                    #pragma unroll
                    for (int d = 0; d < 4; ++d) pkd[d] = (short)f2bf(fA[i][d]);
                    *(bf16x4*)&S[wbase + (i * 4 + g) * 16] = pkd;
                }
            }
            asm volatile("s_waitcnt lgkmcnt(0)" ::: "memory");
            __builtin_amdgcn_sched_barrier(0);
            bf16x4 fr0, fr1, fr2, fr3;
            {
                unsigned ab = (unsigned)(unsigned long long)&S[0] + lane * 8;
                asm volatile("ds_read_b64_tr_b16 %0, %1 offset:0"    : "=v"(fr0) : "v"(ab) : "memory");
                asm volatile("ds_read_b64_tr_b16 %0, %1 offset:512"  : "=v"(fr1) : "v"(ab) : "memory");
                asm volatile("ds_read_b64_tr_b16 %0, %1 offset:1024" : "=v"(fr2) : "v"(ab) : "memory");
                asm volatile("ds_read_b64_tr_b16 %0, %1 offset:1536" : "=v"(fr3) : "v"(ab) : "memory");
            }
            asm volatile("s_waitcnt lgkmcnt(0)" ::: "memory");
            __builtin_amdgcn_sched_barrier(0);
            bf16x4 frs[4] = {fr0, fr1, fr2, fr3};
            #pragma unroll
            for (int ft = 0; ft < 4; ++ft) {
                bf16x8 af;
                #pragma unroll
                for (int j = 0; j < 4; ++j) af[j] = frs[ft][j];
                #pragma unroll
                for (int j = 4; j < 8; ++j) af[j] = 0;
                f32x4 accv = {0.f, 0.f, 0.f, 0.f};
                accv = __builtin_amdgcn_mfma_f32_16x16x32_bf16(af, badj, accv, 0, 0, 0);
                const int t  = cl;
                const int fs = (ft * 16 + kg * 4) ^ ((t & 7) << 3);
                bf16x4 wv;
                #pragma unroll
                for (int r = 0; r < 4; ++r) {
                    float e = accv[r];
                    e = e > 0.f ? e : __expf(e) - 1.f;
                    wv[r] = (short)f2bf(e);
                }
                *(bf16x4*)&S[t * 64 + fs] = wv;
            }
            if (pp < 3) { fA[0] = fB[0]; fA[1] = fB[1]; fA[2] = fB[2]; fA[3] = fB[3]; }
        }
    }

    __syncthreads();

    // ---- phase 2: wave w owns C-tile rows=16 points, cols c in [16w,16w+16) ----
    const int c = w * 16 + cl;
    f32x4 acc = {0.f, 0.f, 0.f, 0.f};
    #pragma unroll 8
    for (int kt = 0; kt < 32; ++kt) {
        const int t  = kt >> 1;
        const int fs = (((kt & 1) * 32) | (kg * 8)) ^ ((t & 7) << 3);
        bf16x8 afrag = *(const bf16x8*)&yel[cl][t * 64 + fs];   // ds_read_b128
        bf16x8 bfrag;
        const int k0 = kt * 32 + kg * 8;
        if constexpr (MODE >= 1) {
            bfrag = *(const bf16x8*)&Wb[c * FAN + k0];
        } else {
            f32x4 w0 = *(const f32x4*)&W[c * FAN + k0];
            f32x4 w1 = *(const f32x4*)&W[c * FAN + k0 + 4];
            #pragma unroll
            for (int j = 0; j < 4; ++j) {
                bfrag[j]     = (short)f2bf(w0[j]);
                bfrag[j + 4] = (short)f2bf(w1[j]);
            }
        }
        acc = __builtin_amdgcn_mfma_f32_16x16x32_bf16(afrag, bfrag, acc, 0, 0, 0);
    }

    // epilogue: D row = kg*4 + r = local point, col = c
    float bc = bias[c];
    #pragma unroll
    for (int j = 0; j < 4; ++j) {
        int row = kg * 4 + j;
        int nn  = n0 + (row >> 2);
        int pp  = row & 3;
        float val = acc[j] + bc;
        val = val > 0.f ? val : __expf(val) - 1.f;
        if (nn == NPTS - 1) val = 0.f;   // zero_pad: last point zeroed (all b, all c)
        out[(pp * NPTS + nn) * FDIM + c] = val;
    }
}

extern "C" void kernel_launch(void* const* d_in, const int* in_sizes, int n_in,
                              void* d_out, int out_size, void* d_ws, size_t ws_size,
                              hipStream_t stream) {
    const float* x    = (const float*)d_in[0];
    const float* v    = (const float*)d_in[1];
    const float* aw   = (const float*)d_in[2];
    const float* W    = (const float*)d_in[3];
    const float* bias = (const float*)d_in[4];
    const int*   nbr  = (const int*)d_in[5];
    float* out = (float*)d_out;

    const size_t wb_bytes  = (size_t)OUTC * FAN * 2;            // 128 KB
    const size_t xbf_off   = 131072;                            // 128 KB, 16B-aligned
    const size_t xbf_bytes = (size_t)4 * NPTS * FDIM * 2;       // 25.6 MB

    dim3 grid(NPTS / NBL), blk(256);
    if (ws_size >= xbf_off + xbf_bytes) {
        unsigned short* Wb  = (unsigned short*)d_ws;
        unsigned short* xbf = (unsigned short*)((char*)d_ws + xbf_off);
        wconv_kernel<<<dim3(OUTC * FAN / 256), dim3(256), 0, stream>>>(W, Wb);
        xconv_kernel<<<dim3(4 * NPTS * FDIM / 1024), dim3(256), 0, stream>>>(x, xbf);
        paiconv_kernel<2><<<grid, blk, 0, stream>>>(x, xbf, v, aw, W, Wb, bias, nbr, out);
    } else if (ws_size >= wb_bytes) {
        unsigned short* Wb = (unsigned short*)d_ws;
        wconv_kernel<<<dim3(OUTC * FAN / 256), dim3(256), 0, stream>>>(W, Wb);
        paiconv_kernel<1><<<grid, blk, 0, stream>>>(x, (const unsigned short*)nullptr,
                                                    v, aw, W, Wb, bias, nbr, out);
    } else {
        paiconv_kernel<0><<<grid, blk, 0, stream>>>(x, (const unsigned short*)nullptr,
                                                    v, aw, W, (const unsigned short*)nullptr,
                                                    bias, nbr, out);
    }
}